// Round 1
// baseline (742.512 us; speedup 1.0000x reference)
//
#include <hip/hip_runtime.h>

#define E_ 8
#define C_ 1024
#define H_ 2048
#define B_ 8
#define T_ 1024
#define NGRP 64          // B_*E_
#define NROWS 16384      // B_*T_*K

typedef __bf16 bf16x8 __attribute__((ext_vector_type(8)));
typedef float f32x4 __attribute__((ext_vector_type(4)));
typedef unsigned short u16;

__device__ __forceinline__ u16 f2bf(float f) {
  unsigned u = __float_as_uint(f);
  u += 0x7FFFu + ((u >> 16) & 1u);   // RNE; inputs finite
  return (u16)(u >> 16);
}

// async global->LDS, 16B per lane; lds dst is wave-uniform base + lane*16
__device__ __forceinline__ void gl16(const u16* g, u16* l) {
  __builtin_amdgcn_global_load_lds(
      (const __attribute__((address_space(1))) void*)g,
      (__attribute__((address_space(3))) void*)l, 16, 0, 0);
}

// ---------- weights: in [E][R][S] f32 -> out [E][S][R] bf16 (transpose) ----------
__global__ __launch_bounds__(256) void k_wt(const float* __restrict__ in,
                                            u16* __restrict__ out, int R, int S) {
  __shared__ u16 tile[64][66];
  int e = blockIdx.z;
  int s0 = blockIdx.x * 64, r0 = blockIdx.y * 64;
  int tx = threadIdx.x & 15, ty = threadIdx.x >> 4;
  const float* src = in + ((size_t)e * R + r0) * S + s0;
  #pragma unroll
  for (int i = 0; i < 4; ++i) {
    int rr = i * 16 + ty;
    float4 v = *reinterpret_cast<const float4*>(src + (size_t)rr * S + tx * 4);
    tile[rr][tx * 4 + 0] = f2bf(v.x);
    tile[rr][tx * 4 + 1] = f2bf(v.y);
    tile[rr][tx * 4 + 2] = f2bf(v.z);
    tile[rr][tx * 4 + 3] = f2bf(v.w);
  }
  __syncthreads();
  u16* dst = out + ((size_t)e * S + s0) * R + r0;
  #pragma unroll
  for (int i = 0; i < 4; ++i) {
    int ss = i * 16 + ty;
    ushort4 o;
    o.x = tile[tx * 4 + 0][ss];
    o.y = tile[tx * 4 + 1][ss];
    o.z = tile[tx * 4 + 2][ss];
    o.w = tile[tx * 4 + 3][ss];
    *reinterpret_cast<ushort4*>(dst + (size_t)ss * R + tx * 4) = o;
  }
}

// ---------- router: one wave per token; also emits x as bf16 ----------
__global__ __launch_bounds__(256) void k_router(const float* __restrict__ x,
                                                const float* __restrict__ rw,
                                                u16* __restrict__ xb,
                                                int* __restrict__ counts,
                                                int* __restrict__ tok,
                                                float* __restrict__ pw) {
  int lane = threadIdx.x & 63;
  int tt = blockIdx.x * 4 + (threadIdx.x >> 6);    // token id 0..8191
  const float* xr = x + (size_t)tt * C_;
  u16* xo = xb + (size_t)tt * C_;
  float acc[8] = {0, 0, 0, 0, 0, 0, 0, 0};
  for (int j = 0; j < 16; ++j) {
    int c = j * 64 + lane;
    float xv = xr[c];
    xo[c] = f2bf(xv);
    float4 r0 = reinterpret_cast<const float4*>(rw + c * 8)[0];
    float4 r1 = reinterpret_cast<const float4*>(rw + c * 8)[1];
    acc[0] += xv * r0.x; acc[1] += xv * r0.y; acc[2] += xv * r0.z; acc[3] += xv * r0.w;
    acc[4] += xv * r1.x; acc[5] += xv * r1.y; acc[6] += xv * r1.z; acc[7] += xv * r1.w;
  }
  #pragma unroll
  for (int e = 0; e < 8; ++e)
    #pragma unroll
    for (int off = 32; off; off >>= 1)
      acc[e] += __shfl_xor(acc[e], off);
  if (lane == 0) {
    int b = tt >> 10, t = tt & (T_ - 1);
    int e0 = 0;
    #pragma unroll
    for (int e = 1; e < 8; ++e) if (acc[e] > acc[e0]) e0 = e;   // ties -> lower idx
    int e1 = -1;
    #pragma unroll
    for (int e = 0; e < 8; ++e)
      if (e != e0 && (e1 < 0 || acc[e] > acc[e1])) e1 = e;
    float l0 = acc[e0], l1 = acc[e1];
    float p0 = 1.f / (1.f + expf(l1 - l0));
    float p1 = 1.f / (1.f + expf(l0 - l1));
    int g0 = b * 8 + e0, g1 = b * 8 + e1;
    int s0 = atomicAdd(&counts[g0], 1);
    tok[g0 * T_ + s0] = t; pw[g0 * T_ + s0] = p0;
    int s1 = atomicAdd(&counts[g1], 1);
    tok[g1 * T_ + s1] = t; pw[g1 * T_ + s1] = p1;
  }
}

// ---------- exclusive prefix over 64 counts ----------
__global__ void k_prefix(const int* __restrict__ counts, int* __restrict__ offsets) {
  if (threadIdx.x == 0) {
    int s = 0;
    for (int i = 0; i < NGRP; ++i) { offsets[i] = s; s += counts[i]; }
    offsets[NGRP] = s;
  }
}

// ---------- GEMM1: inter = (Xe@Wfc+bfc) * silu(Xe@Wg+bg), bf16 out ----------
// m97 structure: BM=128 rows x BN=64 cols, dual-B, BK=64, global_load_lds(16B).
// 1-D grid, expert = bid&7 (XCD pin). Per expert: 4 col-chunks x 64 (b,rowtile) x 8 cols.
__global__ __launch_bounds__(256) void k_ffn1(
    const u16* __restrict__ xb, const u16* __restrict__ wfcT, const u16* __restrict__ wgT,
    const float* __restrict__ bfc, const float* __restrict__ bg,
    const int* __restrict__ counts, const int* __restrict__ offsets,
    const int* __restrict__ tok, u16* __restrict__ inter) {
  int bid = blockIdx.x;
  int e = bid & 7;
  int r = bid >> 3;                 // [0,2048)
  int chunk = r >> 9;               // [0,4)   8-coltile chunk (2MB weights -> L2)
  int rr = r & 511;
  int brt = rr >> 3;                // [0,64)  (b, rowtile)
  int col = (chunk << 3) | (rr & 7);
  int b = brt >> 3, rt = brt & 7;
  int g = b * 8 + e;
  int n = counts[g];
  int row0 = rt * 128;
  if (row0 >= n) return;
  int col0 = col * 64;

  __shared__ u16 As[128 * 64];      // 16 KB
  __shared__ u16 Bf[64 * 64];       // 8 KB
  __shared__ u16 Bg[64 * 64];       // 8 KB

  int tid = threadIdx.x;
  int lane = tid & 63, wid = tid >> 6;
  int wr = wid >> 1, wc = wid & 1;
  int fr = lane & 15, fq = lane >> 4;

  // staging addresses: chunk c covers As[c*8 .. c*8+7] (u16) = row c>>3, kcol (c&7)*8
  const u16* sA[4]; u16* lA[4];
  const u16* sF[2]; const u16* sG[2]; u16* lF[2]; u16* lG[2];
  #pragma unroll
  for (int i = 0; i < 4; ++i) {
    int ck = (wid * 4 + i) * 64 + lane;
    int row = ck >> 3, kc = (ck & 7) * 8;
    int slot = row0 + row;
    int t = tok[g * T_ + (slot < n ? slot : n - 1)];
    sA[i] = xb + ((size_t)(b * T_ + t)) * C_ + kc;
    lA[i] = (u16*)As + (size_t)(wid * 4 + i) * 512;
  }
  #pragma unroll
  for (int i = 0; i < 2; ++i) {
    int ck = (wid * 2 + i) * 64 + lane;
    int row = ck >> 3, kc = (ck & 7) * 8;
    sF[i] = wfcT + ((size_t)e * H_ + col0 + row) * C_ + kc;
    sG[i] = wgT + ((size_t)e * H_ + col0 + row) * C_ + kc;
    lF[i] = (u16*)Bf + (size_t)(wid * 2 + i) * 512;
    lG[i] = (u16*)Bg + (size_t)(wid * 2 + i) * 512;
  }

  f32x4 ah[4][2] = {}; f32x4 ag[4][2] = {};

  for (int kt = 0; kt < C_; kt += 64) {
    __syncthreads();
    #pragma unroll
    for (int i = 0; i < 4; ++i) gl16(sA[i] + kt, lA[i]);
    #pragma unroll
    for (int i = 0; i < 2; ++i) { gl16(sF[i] + kt, lF[i]); gl16(sG[i] + kt, lG[i]); }
    __syncthreads();
    #pragma unroll
    for (int kk = 0; kk < 2; ++kk) {
      bf16x8 a[4], f[2], gg[2];
      #pragma unroll
      for (int m = 0; m < 4; ++m)
        a[m] = *reinterpret_cast<const bf16x8*>(&As[(wr * 64 + m * 16 + fr) * 64 + kk * 32 + fq * 8]);
      #pragma unroll
      for (int j = 0; j < 2; ++j) {
        f[j]  = *reinterpret_cast<const bf16x8*>(&Bf[(wc * 32 + j * 16 + fr) * 64 + kk * 32 + fq * 8]);
        gg[j] = *reinterpret_cast<const bf16x8*>(&Bg[(wc * 32 + j * 16 + fr) * 64 + kk * 32 + fq * 8]);
      }
      #pragma unroll
      for (int m = 0; m < 4; ++m)
        #pragma unroll
        for (int j = 0; j < 2; ++j) {
          ah[m][j] = __builtin_amdgcn_mfma_f32_16x16x32_bf16(a[m], f[j],  ah[m][j], 0, 0, 0);
          ag[m][j] = __builtin_amdgcn_mfma_f32_16x16x32_bf16(a[m], gg[j], ag[m][j], 0, 0, 0);
        }
    }
  }
  int base = offsets[g];
  #pragma unroll
  for (int m = 0; m < 4; ++m) {
    #pragma unroll
    for (int rj = 0; rj < 4; ++rj) {
      int slot = row0 + wr * 64 + m * 16 + fq * 4 + rj;
      if (slot < n) {
        size_t rowb = (size_t)(base + slot) * H_;
        #pragma unroll
        for (int j = 0; j < 2; ++j) {
          int hc = col0 + wc * 32 + j * 16 + fr;
          float h  = ah[m][j][rj] + bfc[e * H_ + hc];
          float gp = ag[m][j][rj] + bg[e * H_ + hc];
          inter[rowb + hc] = f2bf(h * gp / (1.f + expf(-gp)));   // h * silu(gp)
        }
      }
    }
  }
}

// ---------- GEMM2: o = inter@Wproj + bp ; y[t] += p*o (atomic scatter) ----------
// m97 structure: BM=128 x BN=128, BK=64. Expert weights (4MB) L2-resident per XCD.
__global__ __launch_bounds__(256) void k_ffn2(
    const u16* __restrict__ inter, const u16* __restrict__ wpT,
    const float* __restrict__ bp,
    const int* __restrict__ counts, const int* __restrict__ offsets,
    const int* __restrict__ tok, const float* __restrict__ pw,
    float* __restrict__ y) {
  int bid = blockIdx.x;
  int e = bid & 7;
  int r = bid >> 3;                 // [0,512)
  int brt = r >> 3;                 // [0,64) (b,rowtile) outer; col inner (A reuse)
  int col = r & 7;
  int b = brt >> 3, rt = brt & 7;
  int g = b * 8 + e;
  int n = counts[g];
  int row0 = rt * 128;
  if (row0 >= n) return;
  int col0 = col * 128;
  int base = offsets[g];

  __shared__ u16 As[128 * 64];      // 16 KB
  __shared__ u16 Bs[128 * 64];      // 16 KB

  int tid = threadIdx.x;
  int lane = tid & 63, wid = tid >> 6;
  int wr = wid >> 1, wc = wid & 1;
  int fr = lane & 15, fq = lane >> 4;

  const u16* sA[4]; const u16* sB[4]; u16* lA[4]; u16* lB[4];
  #pragma unroll
  for (int i = 0; i < 4; ++i) {
    int ck = (wid * 4 + i) * 64 + lane;
    int row = ck >> 3, kc = (ck & 7) * 8;
    int slot = row0 + row;
    int rg = base + (slot < n ? slot : n - 1);   // clamp into valid compacted rows
    sA[i] = inter + (size_t)rg * H_ + kc;
    sB[i] = wpT + ((size_t)e * C_ + col0 + row) * H_ + kc;
    lA[i] = (u16*)As + (size_t)(wid * 4 + i) * 512;
    lB[i] = (u16*)Bs + (size_t)(wid * 4 + i) * 512;
  }

  f32x4 acc[4][4] = {};

  for (int kt = 0; kt < H_; kt += 64) {
    __syncthreads();
    #pragma unroll
    for (int i = 0; i < 4; ++i) { gl16(sA[i] + kt, lA[i]); gl16(sB[i] + kt, lB[i]); }
    __syncthreads();
    #pragma unroll
    for (int kk = 0; kk < 2; ++kk) {
      bf16x8 a[4], bb[4];
      #pragma unroll
      for (int m = 0; m < 4; ++m)
        a[m] = *reinterpret_cast<const bf16x8*>(&As[(wr * 64 + m * 16 + fr) * 64 + kk * 32 + fq * 8]);
      #pragma unroll
      for (int j = 0; j < 4; ++j)
        bb[j] = *reinterpret_cast<const bf16x8*>(&Bs[(wc * 64 + j * 16 + fr) * 64 + kk * 32 + fq * 8]);
      #pragma unroll
      for (int m = 0; m < 4; ++m)
        #pragma unroll
        for (int j = 0; j < 4; ++j)
          acc[m][j] = __builtin_amdgcn_mfma_f32_16x16x32_bf16(a[m], bb[j], acc[m][j], 0, 0, 0);
    }
  }
  #pragma unroll
  for (int m = 0; m < 4; ++m) {
    #pragma unroll
    for (int rj = 0; rj < 4; ++rj) {
      int slot = row0 + wr * 64 + m * 16 + fq * 4 + rj;
      if (slot < n) {
        int t = tok[g * T_ + slot];
        float p = pw[g * T_ + slot];
        float* yr = y + ((size_t)(b * T_ + t)) * C_;
        #pragma unroll
        for (int j = 0; j < 4; ++j) {
          int cc = col0 + wc * 64 + j * 16 + fr;
          float v = acc[m][j][rj] + bp[e * C_ + cc];
          atomicAdd(&yr[cc], p * v);
        }
      }
    }
  }
}

extern "C" void kernel_launch(void* const* d_in, const int* in_sizes, int n_in,
                              void* d_out, int out_size, void* d_ws, size_t ws_size,
                              hipStream_t stream) {
  const float* x   = (const float*)d_in[0];
  const float* rw  = (const float*)d_in[1];
  const float* wfc = (const float*)d_in[2];
  const float* bfc = (const float*)d_in[3];
  const float* wg  = (const float*)d_in[4];
  const float* bg  = (const float*)d_in[5];
  const float* wp  = (const float*)d_in[6];
  const float* bp  = (const float*)d_in[7];
  float* y = (float*)d_out;

  char* ws = (char*)d_ws;
  // ws layout (bytes)
  const size_t OFF_COUNTS  = 0;                      // 64 ints
  const size_t OFF_OFFSETS = 1024;                   // 65 ints
  const size_t OFF_TOK     = 2048;                   // 64*1024 ints   = 256 KB
  const size_t OFF_PW      = OFF_TOK + 262144;       // 256 KB
  const size_t OFF_XB      = OFF_PW + 262144;        // 16 MB bf16 x
  const size_t OFF_WFCT    = OFF_XB + (size_t)B_ * T_ * C_ * 2;       // 32 MB
  const size_t OFF_WGT     = OFF_WFCT + (size_t)E_ * C_ * H_ * 2;     // 32 MB
  const size_t OFF_WPT     = OFF_WGT + (size_t)E_ * C_ * H_ * 2;      // 32 MB
  const size_t OFF_INTER   = OFF_WPT + (size_t)E_ * H_ * C_ * 2;      // 64 MB
  int*   counts  = (int*)(ws + OFF_COUNTS);
  int*   offsets = (int*)(ws + OFF_OFFSETS);
  int*   tok     = (int*)(ws + OFF_TOK);
  float* pw      = (float*)(ws + OFF_PW);
  u16*   xb      = (u16*)(ws + OFF_XB);
  u16*   wfcT    = (u16*)(ws + OFF_WFCT);
  u16*   wgT     = (u16*)(ws + OFF_WGT);
  u16*   wpT     = (u16*)(ws + OFF_WPT);
  u16*   inter   = (u16*)(ws + OFF_INTER);

  hipMemsetAsync(d_out, 0, (size_t)out_size * sizeof(float), stream);
  hipMemsetAsync(counts, 0, 256, stream);

  k_wt<<<dim3(H_ / 64, C_ / 64, E_), 256, 0, stream>>>(wfc, wfcT, C_, H_);
  k_wt<<<dim3(H_ / 64, C_ / 64, E_), 256, 0, stream>>>(wg, wgT, C_, H_);
  k_wt<<<dim3(C_ / 64, H_ / 64, E_), 256, 0, stream>>>(wp, wpT, H_, C_);
  k_router<<<(B_ * T_) / 4, 256, 0, stream>>>(x, rw, xb, counts, tok, pw);
  k_prefix<<<1, 64, 0, stream>>>(counts, offsets);
  k_ffn1<<<E_ * 4 * 64 * 8, 256, 0, stream>>>(          // 16384 blocks
      xb, wfcT, wgT, bfc, bg, counts, offsets, tok, inter);
  k_ffn2<<<E_ * 64 * 8, 256, 0, stream>>>(              // 4096 blocks
      inter, wpT, bp, counts, offsets, tok, pw, y);
  (void)in_sizes; (void)n_in; (void)ws_size;
}